// Round 4
// baseline (7667.953 us; speedup 1.0000x reference)
//
#include <hip/hip_runtime.h>
#include <stdint.h>

// ---------------------------------------------------------------------------
// GraphRNN-style generator, 2081 strictly-sequential GRU states.
// R4: classifier fused INTO all 16 worker WGs (30-row head matvec replicated,
// +32KB LDS) -> decisions are local, no dec handoff, no classifier WG, no
// classifier lag. Worker 0 writes all outputs from local round buffers.
// 4 helper WGs (down from 12) compute Wih@h1 speculatively with s_sleep
// backoff polling. Communication: proven agent-scope atomics + 0xFF sentinel
// (bit pattern unreachable from finite f32 math), write-once words.
// ---------------------------------------------------------------------------

#define H 256
#define HL 128
#define G3 768
#define NW 16
#define SL 16                       // H / NW
#define MAXN 64
#define NSTATE (1 + MAXN + (MAXN*(MAXN-1))/2)   // 2081
#define SENTU 0xFFFFFFFFu
#define PAD 264
#define NHELP 4
#define NWG (NW + NHELP)            // 20

// output layout (f32 words), total 20928
#define NP_OFF 0
#define NI_OFF 192
#define NV_OFF 384
#define EP_OFF 448
#define EI_OFF (EP_OFF + MAXN*MAXN*2)   // 8640
#define EV_OFF (EI_OFF + MAXN*MAXN*2)   // 16832

struct Wksp {
  float h[NSTATE][H];          // full hidden-state history (write-once words)
  float gi_e[MAXN][G3];        // eWih @ h1_i (speculative, no bias)
  float gi_n[MAXN][G3];        // nWih @ h1_i
};

union Shm {
  struct {
    float whe[3*SL*PAD];       // eWhh rows {gate*256+k} for this WG's 16 k's
    float whn[3*SL*PAD];       // nWhh rows
    float cw[30*PAD];          // classifier rows: nc0(12) nc1(5) nc2(4) ec0(5) ec1(4)
    float hg[H];               // gathered state (generic)
    float h1s[H];              // stash of current round's node state h1_i
    float hkeep[H];            // node-GRU h input (reference's running h)
    float own[SL];             // own 16-slice of last published state
    float bihe[3*SL], bhhe[3*SL], bihn[3*SL], bhhn[3*SL];
    float cb[30];
    float zv[HL];
    float logits[30];
    // round buffers (flushed at boundary by worker 0)
    float np[3];  int ni[3];
    float ep0[MAXN], ep1[MAXN];
    int   ei0[MAXN], ei1[MAXN];
    unsigned int isend, andflag;
  } w;
  struct { float h1[H]; } hp;
};

__device__ __forceinline__ float spinf(const float* p) {
  const unsigned int* u = (const unsigned int*)p;
  unsigned int v = __hip_atomic_load(u, __ATOMIC_RELAXED, __HIP_MEMORY_SCOPE_AGENT);
  while (v == SENTU)
    v = __hip_atomic_load(u, __ATOMIC_RELAXED, __HIP_MEMORY_SCOPE_AGENT);
  return __uint_as_float(v);
}
__device__ __forceinline__ float spinf_slow(const float* p) {
  const unsigned int* u = (const unsigned int*)p;
  unsigned int v = __hip_atomic_load(u, __ATOMIC_RELAXED, __HIP_MEMORY_SCOPE_AGENT);
  while (v == SENTU) {
    __builtin_amdgcn_s_sleep(1);
    v = __hip_atomic_load(u, __ATOMIC_RELAXED, __HIP_MEMORY_SCOPE_AGENT);
  }
  return __uint_as_float(v);
}
__device__ __forceinline__ void pubf(float* p, float x) {
  __hip_atomic_store((unsigned int*)p, __float_as_uint(x),
                     __ATOMIC_RELAXED, __HIP_MEMORY_SCOPE_AGENT);
}
__device__ __forceinline__ float sigm(float x) { return 1.0f / (1.0f + expf(-x)); }

__global__ __launch_bounds__(256)
void Generator_34746285425383_kernel(
    const float* __restrict__ z, const float* __restrict__ lp_w, const float* __restrict__ lp_b,
    const float* __restrict__ nWih, const float* __restrict__ nWhh,
    const float* __restrict__ nbih, const float* __restrict__ nbhh,
    const float* __restrict__ eWih, const float* __restrict__ eWhh,
    const float* __restrict__ ebih, const float* __restrict__ ebhh,
    const float* __restrict__ nc0w, const float* __restrict__ nc0b,
    const float* __restrict__ nc1w, const float* __restrict__ nc1b,
    const float* __restrict__ nc2w, const float* __restrict__ nc2b,
    const float* __restrict__ ec0w, const float* __restrict__ ec0b,
    const float* __restrict__ ec1w, const float* __restrict__ ec1b,
    float* __restrict__ out, Wksp* __restrict__ ws)
{
  __shared__ Shm S;
  const int bid = blockIdx.x;
  const int tid = threadIdx.x;

  if (bid < NW) {
    // =================== WORKER (GRU slice + replicated classifier) =========
    const int w = bid, g = tid >> 4, c = tid & 15;
    const int k = w * SL + g;
    for (int r = 0; r < 3 * SL; ++r) {
      const int gate = r / SL, gg = r % SL;
      const int grow = gate * H + (w * SL + gg);
      for (int col = tid; col < H; col += 256) {
        S.w.whe[r * PAD + col] = eWhh[grow * H + col];
        S.w.whn[r * PAD + col] = nWhh[grow * H + col];
      }
    }
    {
      const float* wsrc[5] = { nc0w, nc1w, nc2w, ec0w, ec1w };
      const float* bsrc[5] = { nc0b, nc1b, nc2b, ec0b, ec1b };
      const int hbase[5] = { 0, 12, 17, 21, 26 };
      const int hlen[5]  = { 12, 5, 4, 5, 4 };
      for (int hh = 0; hh < 5; ++hh)
        for (int r = 0; r < hlen[hh]; ++r)
          for (int col = tid; col < H; col += 256)
            S.w.cw[(hbase[hh] + r) * PAD + col] = wsrc[hh][r * H + col];
      if (tid < 30) {
        const int hh = tid < 12 ? 0 : tid < 17 ? 1 : tid < 21 ? 2 : tid < 26 ? 3 : 4;
        S.w.cb[tid] = bsrc[hh][tid - hbase[hh]];
      }
    }
    if (tid < 3 * SL) {
      const int gate = tid / SL, gg = tid % SL;
      const int grow = gate * H + w * SL + gg;
      S.w.bihe[tid] = ebih[grow]; S.w.bhhe[tid] = ebhh[grow];
      S.w.bihn[tid] = nbih[grow]; S.w.bhhn[tid] = nbhh[grow];
    }
    if (tid < HL) S.w.zv[tid] = z[tid];
    if (tid == 0) { S.w.andflag = 1u; S.w.isend = 0u; }
    __syncthreads();

    // state 0: h0 = z @ lp_w.T + lp_b
    {
      float p = 0.f;
      for (int it = 0; it < 8; ++it) {
        const int col = c + 16 * it;
        p += S.w.zv[col] * lp_w[k * HL + col];
      }
      for (int off = 1; off < 16; off <<= 1) p += __shfl_xor(p, off);
      const float hp = p + lp_b[k];
      if (c == 0) pubf(&ws->h[0][k], hp);
      if (c == 1) S.w.own[g] = hp;
    }
    __syncthreads();

    int m = 1;
    bool done = false;
    unsigned long long valid = 0ull;
    float pg0 = 0.f, pg1 = 0.f, pg2 = 0.f;
    const float* pga = nullptr;

    for (int i = 0; i < MAXN; ++i) {
      for (int t = -1; t < i; ++t) {        // t=-1: node step, t>=0: edge steps
        const bool is_node = (t < 0);
        float* dst = (t == 0) ? S.w.h1s : S.w.hg;
        // ---- gather h[m-1] (always the just-published state) ----
        {
          const bool ownfast = (tid >= w * SL) && (tid < w * SL + SL);
          dst[tid] = ownfast ? S.w.own[tid - w * SL] : spinf(&ws->h[m - 1][tid]);
        }
        __syncthreads();                    // B1
        // ---- classify gathered state (skip only the very first gather h[0]) ----
        const bool do_cls = !(is_node && i == 0);
        if (do_cls) {
          for (int rsel = 0; rsel < 2; ++rsel) {
            const int r = g + 16 * rsel;
            float p = 0.f;
            if (r < 30) {
              #pragma unroll
              for (int it = 0; it < 16; ++it) {
                const int col = c + 16 * it;
                p += S.w.cw[r * PAD + col] * dst[col];
              }
            }
            for (int off = 1; off < 16; off <<= 1) p += __shfl_xor(p, off);
            if (r < 30 && c == 0) S.w.logits[r] = p + S.w.cb[r];
          }
        }
        // ---- boundary (node step, i>0): finalize round r=i-1 before the GRU ----
        if (is_node && i > 0) {
          const int r_ = i - 1;
          __syncthreads();                  // B2: logits visible
          if (tid < 5) {                    // head reduce (serial per head, as R1)
            const int base = tid == 0 ? 0 : tid == 1 ? 12 : tid == 2 ? 17 : tid == 3 ? 21 : 26;
            const int len  = tid == 0 ? 12 : tid == 1 ? 5 : tid == 2 ? 4 : tid == 3 ? 5 : 4;
            float best = S.w.logits[base]; int bi = 0;
            for (int j = 1; j < len; ++j) {
              const float l = S.w.logits[base + j];
              if (l > best) { best = l; bi = j; }
            }
            float s = 0.f;
            for (int j = 0; j < len; ++j) s += expf(S.w.logits[base + j] - best);
            const float pm = 1.0f / s;
            if (r_ == 0) {                  // boundary state IS round-0's node state
              if (tid < 3) { S.w.np[tid] = pm; S.w.ni[tid] = bi;
                             if (tid == 0) S.w.isend = (bi == 11) ? 1u : 0u; }
              if (tid == 3) { S.w.ep0[0] = pm; S.w.ei0[0] = bi; }
              if (tid == 4) { S.w.ep1[0] = pm; S.w.ei1[0] = bi; }
            } else {                        // last edge state of round r_ -> slot r_-1
              if (tid == 3) { S.w.ep0[r_ - 1] = pm; S.w.ei0[r_ - 1] = bi;
                              if (bi != 0) S.w.andflag = 0u; }
              if (tid == 4) { S.w.ep1[r_ - 1] = pm; S.w.ei1[r_ - 1] = bi; }
            }
          }
          __syncthreads();                  // B3
          const bool is_end   = S.w.isend != 0u;
          const bool no_edges = (r_ > 0) && (S.w.andflag != 0u);
          const bool active   = !done;
          const bool node_ok  = active && !is_end && !no_edges;
          if (node_ok) valid |= (1ull << r_);
          if (w == 0) {                     // flush outputs of round r_
            if (tid < MAXN) {
              const int j = tid;
              const bool vj = j < r_;
              const bool ev = vj && node_ok && (r_ > 0);
              const int tt = vj ? (r_ - 1 - j) : 0;
              out[EP_OFF + (r_ * MAXN + j) * 2 + 0] = ev ? S.w.ep0[tt] : 0.f;
              out[EP_OFF + (r_ * MAXN + j) * 2 + 1] = ev ? S.w.ep1[tt] : 0.f;
              out[EI_OFF + (r_ * MAXN + j) * 2 + 0] = (float)S.w.ei0[tt];
              out[EI_OFF + (r_ * MAXN + j) * 2 + 1] = (float)S.w.ei1[tt];
              out[EV_OFF + r_ * MAXN + j] = ev ? 1.f : 0.f;
            } else if (tid < MAXN + 8) {
              const int q = tid - MAXN;
              if (q < 3)       out[NP_OFF + r_ * 3 + q]       = node_ok ? S.w.np[q] : 0.f;
              else if (q < 6)  out[NI_OFF + r_ * 3 + (q - 3)] = (float)S.w.ni[q - 3];
              else if (q == 6) out[NV_OFF + r_]               = node_ok ? 1.f : 0.f;
            }
          }
          if (active) {                     // update running-h for the node GRU
            const bool useg = (node_ok && r_ > 0) || (r_ == 0);
            S.w.hkeep[tid] = useg ? S.w.hg[tid] : S.w.h1s[tid];
          }
          done = done || is_end || no_edges;
          __syncthreads();                  // B4
          if (tid == 0) S.w.andflag = 1u;   // reset for round i (next write >= 2 barriers away)
        }
        // ---- GRU for state m ----
        const float* hb = is_node ? (i == 0 ? S.w.hg : S.w.hkeep) : dst;
        const int src = is_node ? (i - 1) : (i - 1 - t);
        float gi0 = 0.f, gi1 = 0.f, gi2 = 0.f;
        const bool use_gi = (src >= 0) && ((valid >> src) & 1ull);
        if (use_gi) {
          gi0 = pg0; gi1 = pg1; gi2 = pg2;
          if (__float_as_uint(gi0) == SENTU) gi0 = spinf(&pga[0 * H + k]);
          if (__float_as_uint(gi1) == SENTU) gi1 = spinf(&pga[1 * H + k]);
          if (__float_as_uint(gi2) == SENTU) gi2 = spinf(&pga[2 * H + k]);
        }
        const float* Wl = is_node ? S.w.whn : S.w.whe;
        float p0 = 0.f, p1 = 0.f, p2 = 0.f;
        #pragma unroll
        for (int it = 0; it < 16; ++it) {
          const int col = c + 16 * it;
          const float hv = hb[col];
          p0 += Wl[(0 * SL + g) * PAD + col] * hv;
          p1 += Wl[(1 * SL + g) * PAD + col] * hv;
          p2 += Wl[(2 * SL + g) * PAD + col] * hv;
        }
        for (int off = 1; off < 16; off <<= 1) {
          p0 += __shfl_xor(p0, off);
          p1 += __shfl_xor(p1, off);
          p2 += __shfl_xor(p2, off);
        }
        const float* bih = is_node ? S.w.bihn : S.w.bihe;
        const float* bhh = is_node ? S.w.bhhn : S.w.bhhe;
        const float rr = sigm(gi0 + bih[0 * SL + g] + p0 + bhh[0 * SL + g]);
        const float zz = sigm(gi1 + bih[1 * SL + g] + p1 + bhh[1 * SL + g]);
        const float nn = tanhf(gi2 + bih[2 * SL + g] + rr * (p2 + bhh[2 * SL + g]));
        const float hp = (1.f - zz) * nn + zz * hb[k];
        if (c == 0) pubf(&ws->h[m][k], hp);
        if (c == 1) S.w.own[g] = hp;
        // prefetch next state's gi words
        {
          int ni_ = i, nt_ = t + 1;
          if (nt_ >= i) { ni_ = i + 1; nt_ = -1; }
          if (ni_ < MAXN) {
            const bool nnode = (nt_ < 0);
            const int nsrc = nnode ? (ni_ - 1) : (ni_ - 1 - nt_);
            if (nsrc >= 0) {
              pga = nnode ? ws->gi_n[nsrc] : ws->gi_e[nsrc];
              pg0 = __builtin_nontemporal_load(&pga[0 * H + k]);
              pg1 = __builtin_nontemporal_load(&pga[1 * H + k]);
              pg2 = __builtin_nontemporal_load(&pga[2 * H + k]);
            }
          }
        }
        __syncthreads();                    // Btrail (logits/own/dst protected)
        // ---- stash classification of state m-1 (edge-path; node-state or eslot) ----
        if (!is_node && tid < 5) {
          const int base = tid == 0 ? 0 : tid == 1 ? 12 : tid == 2 ? 17 : tid == 3 ? 21 : 26;
          const int len  = tid == 0 ? 12 : tid == 1 ? 5 : tid == 2 ? 4 : tid == 3 ? 5 : 4;
          float best = S.w.logits[base]; int bi = 0;
          for (int j = 1; j < len; ++j) {
            const float l = S.w.logits[base + j];
            if (l > best) { best = l; bi = j; }
          }
          float s = 0.f;
          for (int j = 0; j < len; ++j) s += expf(S.w.logits[base + j] - best);
          const float pm = 1.0f / s;
          if (t == 0) {                     // gathered = node state h1_i
            if (tid < 3) { S.w.np[tid] = pm; S.w.ni[tid] = bi;
                           if (tid == 0) S.w.isend = (bi == 11) ? 1u : 0u; }
          } else {                          // gathered = edge state slot t-1
            if (tid == 3) { S.w.ep0[t - 1] = pm; S.w.ei0[t - 1] = bi;
                            if (bi != 0) S.w.andflag = 0u; }
            if (tid == 4) { S.w.ep1[t - 1] = pm; S.w.ei1[t - 1] = bi; }
          }
        }
        ++m;
      }
    }

    // ---- epilogue: classify h[2080], finalize & flush round 63 ----
    {
      const int r_ = MAXN - 1;
      float* dst = S.w.hg;
      {
        const bool ownfast = (tid >= w * SL) && (tid < w * SL + SL);
        dst[tid] = ownfast ? S.w.own[tid - w * SL] : spinf(&ws->h[NSTATE - 1][tid]);
      }
      __syncthreads();
      for (int rsel = 0; rsel < 2; ++rsel) {
        const int r = g + 16 * rsel;
        float p = 0.f;
        if (r < 30) {
          #pragma unroll
          for (int it = 0; it < 16; ++it) {
            const int col = c + 16 * it;
            p += S.w.cw[r * PAD + col] * dst[col];
          }
        }
        for (int off = 1; off < 16; off <<= 1) p += __shfl_xor(p, off);
        if (r < 30 && c == 0) S.w.logits[r] = p + S.w.cb[r];
      }
      __syncthreads();
      if (tid < 5) {
        const int base = tid == 0 ? 0 : tid == 1 ? 12 : tid == 2 ? 17 : tid == 3 ? 21 : 26;
        const int len  = tid == 0 ? 12 : tid == 1 ? 5 : tid == 2 ? 4 : tid == 3 ? 5 : 4;
        float best = S.w.logits[base]; int bi = 0;
        for (int j = 1; j < len; ++j) {
          const float l = S.w.logits[base + j];
          if (l > best) { best = l; bi = j; }
        }
        float s = 0.f;
        for (int j = 0; j < len; ++j) s += expf(S.w.logits[base + j] - best);
        const float pm = 1.0f / s;
        if (tid == 3) { S.w.ep0[r_ - 1] = pm; S.w.ei0[r_ - 1] = bi;
                        if (bi != 0) S.w.andflag = 0u; }
        if (tid == 4) { S.w.ep1[r_ - 1] = pm; S.w.ei1[r_ - 1] = bi; }
      }
      __syncthreads();
      if (w == 0) {
        const bool is_end   = S.w.isend != 0u;
        const bool no_edges = S.w.andflag != 0u;   // r_ = 63 > 0
        const bool active   = !done;
        const bool node_ok  = active && !is_end && !no_edges;
        if (tid < MAXN) {
          const int j = tid;
          const bool vj = j < r_;
          const bool ev = vj && node_ok;
          const int tt = vj ? (r_ - 1 - j) : 0;
          out[EP_OFF + (r_ * MAXN + j) * 2 + 0] = ev ? S.w.ep0[tt] : 0.f;
          out[EP_OFF + (r_ * MAXN + j) * 2 + 1] = ev ? S.w.ep1[tt] : 0.f;
          out[EI_OFF + (r_ * MAXN + j) * 2 + 0] = (float)S.w.ei0[tt];
          out[EI_OFF + (r_ * MAXN + j) * 2 + 1] = (float)S.w.ei1[tt];
          out[EV_OFF + r_ * MAXN + j] = ev ? 1.f : 0.f;
        } else if (tid < MAXN + 8) {
          const int q = tid - MAXN;
          if (q < 3)       out[NP_OFF + r_ * 3 + q]       = node_ok ? S.w.np[q] : 0.f;
          else if (q < 6)  out[NI_OFF + r_ * 3 + (q - 3)] = (float)S.w.ni[q - 3];
          else if (q == 6) out[NV_OFF + r_]               = node_ok ? 1.f : 0.f;
        }
      }
    }

  } else {
    // =================== Gi HELPERS (4 WGs, 384 rows each) ===================
    const int e = bid - NW;                 // 0..3
    const bool is_edge = (e < 2);
    const int rowbase = (e & 1) * 384;
    const float* Wih = is_edge ? eWih : nWih;
    float* gdst = is_edge ? &ws->gi_e[0][0] : &ws->gi_n[0][0];
    const int g = tid >> 4, c = tid & 15;
    int m_node = 1;
    for (int i = 0; i < MAXN; ++i) {
      S.hp.h1[tid] = spinf_slow(&ws->h[m_node][tid]);
      __syncthreads();
      for (int rr = 0; rr < 24; ++rr) {
        const int row = rowbase + g * 24 + rr;
        float p = 0.f;
        #pragma unroll
        for (int u = 0; u < 4; ++u) {
          const float4 wv = *(const float4*)&Wih[row * H + c * 16 + u * 4];
          p += wv.x * S.hp.h1[c * 16 + u * 4 + 0]
             + wv.y * S.hp.h1[c * 16 + u * 4 + 1]
             + wv.z * S.hp.h1[c * 16 + u * 4 + 2]
             + wv.w * S.hp.h1[c * 16 + u * 4 + 3];
        }
        for (int off = 1; off < 16; off <<= 1) p += __shfl_xor(p, off);
        if (c == 0) pubf(&gdst[i * G3 + row], p);
      }
      __syncthreads();
      m_node += 1 + i;
    }
  }
}

extern "C" void kernel_launch(void* const* d_in, const int* in_sizes, int n_in,
                              void* d_out, int out_size, void* d_ws, size_t ws_size,
                              hipStream_t stream) {
  // sentinel-fill the communication workspace every call (graph-replay safe)
  hipMemsetAsync(d_ws, 0xFF, sizeof(Wksp), stream);
  Generator_34746285425383_kernel<<<dim3(NWG), dim3(256), 0, stream>>>(
      (const float*)d_in[0],  (const float*)d_in[1],  (const float*)d_in[2],
      (const float*)d_in[3],  (const float*)d_in[4],  (const float*)d_in[5],
      (const float*)d_in[6],  (const float*)d_in[7],  (const float*)d_in[8],
      (const float*)d_in[9],  (const float*)d_in[10],
      (const float*)d_in[11], (const float*)d_in[12],
      (const float*)d_in[13], (const float*)d_in[14],
      (const float*)d_in[15], (const float*)d_in[16],
      (const float*)d_in[17], (const float*)d_in[18],
      (const float*)d_in[19], (const float*)d_in[20],
      (float*)d_out, (Wksp*)d_ws);
}

// Round 5
// 5079.068 us; speedup vs baseline: 1.5097x; 1.5097x over previous
//
#include <hip/hip_runtime.h>
#include <stdint.h>

// ---------------------------------------------------------------------------
// GraphRNN-style generator. 2081 strictly-sequential GRU states distributed
// across 16 worker WGs (h sliced 16 elems each, Whh rows LDS-resident),
// 1 classifier WG (5 softmax heads + all output writes + decisions),
// 12 helper WGs (speculative Wih@h1 per outer step, off critical path).
// Cross-WG sync: sentinel-valued data words (0xFFFFFFFF = -NaN, unreachable
// from finite f32 math), agent-scope atomic load/store, no flags, no fences.
// R5: (a) 227 HEATER WGs (dependent-FMA spin, exit on dec[63]) keep the SMU
// from downclocking the chip while the latency-bound pipeline runs -- the
// 105KB LDS alloc guarantees 1 WG/CU so heaters never share a CU with roles.
// (b) worker inner loop: parity-double-buffered hcur -> ONE barrier/state,
// own-slice fast path dropped (own words ride the same parallel MALL RT).
// ---------------------------------------------------------------------------

#define H 256
#define HL 128
#define G3 768
#define NW 16
#define SL 16                       // H / NW
#define MAXN 64
#define NSTATE (1 + MAXN + (MAXN*(MAXN-1))/2)   // 2081
#define SENTU 0xFFFFFFFFu
#define PAD 264

#define WG_CLS NW                   // role 16
#define WG_HELP0 (NW+1)             // roles 17..28
#define NHELP_PER 6
#define NROLE (WG_HELP0 + 2*NHELP_PER) // 29
#define NWG 256                     // 29 roles + 227 heaters (1 WG/CU via LDS)

// output layout (f32 words), total 20928
#define NP_OFF 0
#define NI_OFF 192
#define NV_OFF 384
#define EP_OFF 448
#define EI_OFF (EP_OFF + MAXN*MAXN*2)   // 8640
#define EV_OFF (EI_OFF + MAXN*MAXN*2)   // 16832

struct Wksp {
  float h[NSTATE][H];          // full hidden-state history (write-once words)
  float gi_e[MAXN][G3];        // eWih @ h1_i (speculative, no bias)
  float gi_n[MAXN][G3];        // nWih @ h1_i
  unsigned int dec[MAXN];      // 1 | is_end<<1 | no_edges<<2 ; dec[63] = exit flag
};

union Shm {
  struct {
    float whe[3*SL*PAD];       // eWhh rows {gate*256+k} for this WG's 16 k's
    float whn[3*SL*PAD];
    float hcur[2][H];          // parity-double-buffered gathered state
    float bihe[3*SL], bhhe[3*SL], bihn[3*SL], bhhn[3*SL];
    float zv[HL];
    unsigned int dec;
  } w;
  struct {
    float cw[30*H];            // nc0(12) nc1(5) nc2(4) ec0(5) ec1(4)
    float cb[30];
    float hc[H];
    float logits[30];
    float resp[5];
    int   resi[5];
    float ept[MAXN][2];
    int   eit[MAXN][2];
  } c;
  struct { float h1[H]; } hp;
};

__device__ __forceinline__ float spinf(const float* p) {
  const unsigned int* u = (const unsigned int*)p;
  unsigned int v = __hip_atomic_load(u, __ATOMIC_RELAXED, __HIP_MEMORY_SCOPE_AGENT);
  while (v == SENTU)
    v = __hip_atomic_load(u, __ATOMIC_RELAXED, __HIP_MEMORY_SCOPE_AGENT);
  return __uint_as_float(v);
}
__device__ __forceinline__ void pubf(float* p, float x) {
  __hip_atomic_store((unsigned int*)p, __float_as_uint(x),
                     __ATOMIC_RELAXED, __HIP_MEMORY_SCOPE_AGENT);
}
__device__ __forceinline__ unsigned int spinu(const unsigned int* p) {
  unsigned int v = __hip_atomic_load(p, __ATOMIC_RELAXED, __HIP_MEMORY_SCOPE_AGENT);
  while (v == SENTU)
    v = __hip_atomic_load(p, __ATOMIC_RELAXED, __HIP_MEMORY_SCOPE_AGENT);
  return v;
}
__device__ __forceinline__ void pubu(unsigned int* p, unsigned int x) {
  __hip_atomic_store(p, x, __ATOMIC_RELAXED, __HIP_MEMORY_SCOPE_AGENT);
}
__device__ __forceinline__ float sigm(float x) { return 1.0f / (1.0f + expf(-x)); }

__global__ __launch_bounds__(256)
void Generator_34746285425383_kernel(
    const float* __restrict__ z, const float* __restrict__ lp_w, const float* __restrict__ lp_b,
    const float* __restrict__ nWih, const float* __restrict__ nWhh,
    const float* __restrict__ nbih, const float* __restrict__ nbhh,
    const float* __restrict__ eWih, const float* __restrict__ eWhh,
    const float* __restrict__ ebih, const float* __restrict__ ebhh,
    const float* __restrict__ nc0w, const float* __restrict__ nc0b,
    const float* __restrict__ nc1w, const float* __restrict__ nc1b,
    const float* __restrict__ nc2w, const float* __restrict__ nc2b,
    const float* __restrict__ ec0w, const float* __restrict__ ec0b,
    const float* __restrict__ ec1w, const float* __restrict__ ec1b,
    float* __restrict__ out, Wksp* __restrict__ ws)
{
  __shared__ Shm S;
  const int bid = blockIdx.x;
  const int tid = threadIdx.x;

  if (bid < NW) {
    // =================== WORKER ===================
    const int w = bid, g = tid >> 4, c = tid & 15;
    const int k = w * SL + g;               // this group's h element
    for (int r = 0; r < 3 * SL; ++r) {
      const int gate = r / SL, gg = r % SL;
      const int grow = gate * H + (w * SL + gg);
      for (int col = tid; col < H; col += 256) {
        S.w.whe[r * PAD + col] = eWhh[grow * H + col];
        S.w.whn[r * PAD + col] = nWhh[grow * H + col];
      }
    }
    if (tid < 3 * SL) {
      const int gate = tid / SL, gg = tid % SL;
      const int grow = gate * H + w * SL + gg;
      S.w.bihe[tid] = ebih[grow]; S.w.bhhe[tid] = ebhh[grow];
      S.w.bihn[tid] = nbih[grow]; S.w.bhhn[tid] = nbhh[grow];
    }
    if (tid < HL) S.w.zv[tid] = z[tid];
    __syncthreads();

    // state 0: h0 = z @ lp_w.T + lp_b
    {
      float p = 0.f;
      for (int it = 0; it < 8; ++it) {
        const int col = c + 16 * it;        // 0..127
        p += S.w.zv[col] * lp_w[k * HL + col];
      }
      for (int off = 1; off < 16; off <<= 1) p += __shfl_xor(p, off);
      if (c == 0) pubf(&ws->h[0][k], p + lp_b[k]);
    }

    int m = 1, idx_carry = 0;
    bool done = false;
    unsigned long long valid = 0ull;
    float pg0 = 0.f, pg1 = 0.f, pg2 = 0.f;
    const float* pga = nullptr;

    for (int i = 0; i < MAXN; ++i) {
      for (int t = -1; t < i; ++t) {        // t=-1: node step, t>=0: edge steps
        const bool is_node = (t < 0);
        const int hidx = is_node ? idx_carry : (m - 1);
        const int src  = is_node ? (i - 1) : (i - 1 - t);
        float* hc = S.w.hcur[m & 1];        // parity buffer for this state
        hc[tid] = spinf(&ws->h[hidx][tid]);
        // x-side: consume prefetched Wih@buf[src] words (sentinel -> respin)
        float gi0 = 0.f, gi1 = 0.f, gi2 = 0.f;
        const bool use_gi = (src >= 0) && ((valid >> src) & 1ull);
        if (use_gi) {
          gi0 = pg0; gi1 = pg1; gi2 = pg2;
          if (__float_as_uint(gi0) == SENTU) gi0 = spinf(&pga[0 * H + k]);
          if (__float_as_uint(gi1) == SENTU) gi1 = spinf(&pga[1 * H + k]);
          if (__float_as_uint(gi2) == SENTU) gi2 = spinf(&pga[2 * H + k]);
        }
        __syncthreads();                    // the ONE barrier per state
        const float* Wl = is_node ? S.w.whn : S.w.whe;
        float p0 = 0.f, p1 = 0.f, p2 = 0.f;
        #pragma unroll
        for (int it = 0; it < 16; ++it) {
          const int col = c + 16 * it;
          const float hv = hc[col];
          p0 += Wl[(0 * SL + g) * PAD + col] * hv;
          p1 += Wl[(1 * SL + g) * PAD + col] * hv;
          p2 += Wl[(2 * SL + g) * PAD + col] * hv;
        }
        for (int off = 1; off < 16; off <<= 1) {
          p0 += __shfl_xor(p0, off);
          p1 += __shfl_xor(p1, off);
          p2 += __shfl_xor(p2, off);
        }
        const float* bih = is_node ? S.w.bihn : S.w.bihe;
        const float* bhh = is_node ? S.w.bhhn : S.w.bhhe;
        const float rr = sigm(gi0 + bih[0 * SL + g] + p0 + bhh[0 * SL + g]);
        const float zz = sigm(gi1 + bih[1 * SL + g] + p1 + bhh[1 * SL + g]);
        const float nn = tanhf(gi2 + bih[2 * SL + g] + rr * (p2 + bhh[2 * SL + g]));
        const float hp = (1.f - zz) * nn + zz * hc[k];
        if (c == 0) pubf(&ws->h[m][k], hp);
        // prefetch next state's gi words (overlaps next gather spin)
        {
          int ni = i, nt = t + 1;
          if (nt >= i) { ni = i + 1; nt = -1; }
          if (ni < MAXN) {
            const bool nnode = (nt < 0);
            const int nsrc = nnode ? (ni - 1) : (ni - 1 - nt);
            if (nsrc >= 0) {
              pga = nnode ? ws->gi_n[nsrc] : ws->gi_e[nsrc];
              pg0 = __builtin_nontemporal_load(&pga[0 * H + k]);
              pg1 = __builtin_nontemporal_load(&pga[1 * H + k]);
              pg2 = __builtin_nontemporal_load(&pga[2 * H + k]);
            }
          }
        }
        ++m;                                // no trailing barrier (parity bufs)
      }
      // boundary: consume classifier decision
      if (tid == 0) S.w.dec = spinu(&ws->dec[i]);
      __syncthreads();
      const unsigned int dec = S.w.dec;
      const bool is_end   = (dec >> 1) & 1u;
      const bool no_edges = (dec >> 2) & 1u;
      const bool active   = !done;
      const bool node_ok  = active && !is_end && !no_edges;
      if (node_ok) valid |= (1ull << i);
      const int s_end = m - 1, node_m = m - 1 - i;
      if (active) idx_carry = (node_ok && i > 0) ? s_end : node_m;
      done = done || is_end || no_edges;
    }

  } else if (bid == WG_CLS) {
    // =================== CLASSIFIER ===================
    const int g = tid >> 4, c = tid & 15;
    const float* wsrc[5] = { nc0w, nc1w, nc2w, ec0w, ec1w };
    const float* bsrc[5] = { nc0b, nc1b, nc2b, ec0b, ec1b };
    const int hbase[5] = { 0, 12, 17, 21, 26 };
    const int hlen[5]  = { 12, 5, 4, 5, 4 };
    for (int hh = 0; hh < 5; ++hh)
      for (int r = 0; r < hlen[hh]; ++r)
        for (int col = tid; col < H; col += 256)
          S.c.cw[(hbase[hh] + r) * H + col] = wsrc[hh][r * H + col];
    if (tid < 30) {
      const int hh = tid < 12 ? 0 : tid < 17 ? 1 : tid < 21 ? 2 : tid < 26 ? 3 : 4;
      S.c.cb[tid] = bsrc[hh][tid - hbase[hh]];
    }
    __syncthreads();

    int m = 1;
    bool done = false;
    for (int i = 0; i < MAXN; ++i) {
      float npmax[3]; int nidx[3];
      bool is_end = false, andacc = true;
      for (int t = -1; t < i; ++t) {
        S.c.hc[tid] = spinf(&ws->h[m][tid]);
        __syncthreads();
        for (int rsel = 0; rsel < 2; ++rsel) {
          const int r = g + 16 * rsel;
          float p = 0.f;
          if (r < 30) {
            #pragma unroll
            for (int it = 0; it < 16; ++it) {
              const int col = c + 16 * it;
              p += S.c.cw[r * H + col] * S.c.hc[col];
            }
          }
          for (int off = 1; off < 16; off <<= 1) p += __shfl_xor(p, off);
          if (r < 30 && c == 0) S.c.logits[r] = p + S.c.cb[r];
        }
        __syncthreads();
        if (tid < 5) {
          const int base = hbase[tid], len = hlen[tid];
          float best = S.c.logits[base]; int bi = 0;
          for (int j = 1; j < len; ++j) {
            const float l = S.c.logits[base + j];
            if (l > best) { best = l; bi = j; }
          }
          float s = 0.f;
          for (int j = 0; j < len; ++j) s += expf(S.c.logits[base + j] - best);
          S.c.resp[tid] = 1.0f / s;
          S.c.resi[tid] = bi;
        }
        __syncthreads();
        if (t < 0) {
          npmax[0] = S.c.resp[0]; npmax[1] = S.c.resp[1]; npmax[2] = S.c.resp[2];
          nidx[0] = S.c.resi[0]; nidx[1] = S.c.resi[1]; nidx[2] = S.c.resi[2];
          is_end = (S.c.resi[0] == 11);            // END_NODE
          if (i == 0 && tid == 0) {                // i=0: ei_t[0] = classify(h1)
            S.c.ept[0][0] = S.c.resp[3]; S.c.ept[0][1] = S.c.resp[4];
            S.c.eit[0][0] = S.c.resi[3]; S.c.eit[0][1] = S.c.resi[4];
          }
        } else {
          if (tid == 0) {
            S.c.ept[t][0] = S.c.resp[3]; S.c.ept[t][1] = S.c.resp[4];
            S.c.eit[t][0] = S.c.resi[3]; S.c.eit[t][1] = S.c.resi[4];
          }
          andacc = andacc && (S.c.resi[3] == 0);
        }
        __syncthreads();
        ++m;
      }
      const bool no_edges = (i > 0) && andacc;
      const bool active = !done;
      const bool node_ok = active && !is_end && !no_edges;
      if (tid == 0)
        pubu(&ws->dec[i], 1u | (is_end ? 2u : 0u) | (no_edges ? 4u : 0u));
      // outputs for row i (all values written every call; invalid -> 0)
      if (tid < MAXN) {
        const int j = tid;
        const bool vj = j < i;
        const bool ev = vj && node_ok && (i > 0);
        const int tt = vj ? (i - 1 - j) : 0;
        out[EP_OFF + (i * MAXN + j) * 2 + 0] = ev ? S.c.ept[tt][0] : 0.f;
        out[EP_OFF + (i * MAXN + j) * 2 + 1] = ev ? S.c.ept[tt][1] : 0.f;
        out[EI_OFF + (i * MAXN + j) * 2 + 0] = (float)S.c.eit[tt][0];
        out[EI_OFF + (i * MAXN + j) * 2 + 1] = (float)S.c.eit[tt][1];
        out[EV_OFF + i * MAXN + j] = ev ? 1.f : 0.f;
      } else if (tid < MAXN + 8) {
        const int q = tid - MAXN;
        if (q < 3)       out[NP_OFF + i * 3 + q]       = node_ok ? npmax[q] : 0.f;
        else if (q < 6)  out[NI_OFF + i * 3 + (q - 3)] = (float)nidx[q - 3];
        else if (q == 6) out[NV_OFF + i]               = node_ok ? 1.f : 0.f;
      }
      done = done || is_end || no_edges;
      __syncthreads();
    }

  } else if (bid < NROLE) {
    // =================== Gi HELPERS ===================
    const int e = bid - WG_HELP0;               // 0..11
    const bool is_edge = (e < NHELP_PER);
    const int rowbase = (e % NHELP_PER) * 128;
    const float* Wih = is_edge ? eWih : nWih;
    float* gdst = is_edge ? &ws->gi_e[0][0] : &ws->gi_n[0][0];
    const int g = tid >> 4, c = tid & 15;
    int m_node = 1;
    for (int i = 0; i < MAXN; ++i) {
      S.hp.h1[tid] = spinf(&ws->h[m_node][tid]);
      __syncthreads();
      for (int rr = 0; rr < 8; ++rr) {
        const int row = rowbase + g * 8 + rr;
        float p = 0.f;
        #pragma unroll
        for (int u = 0; u < 4; ++u) {
          const float4 wv = *(const float4*)&Wih[row * H + c * 16 + u * 4];
          p += wv.x * S.hp.h1[c * 16 + u * 4 + 0]
             + wv.y * S.hp.h1[c * 16 + u * 4 + 1]
             + wv.z * S.hp.h1[c * 16 + u * 4 + 2]
             + wv.w * S.hp.h1[c * 16 + u * 4 + 3];
        }
        for (int off = 1; off < 16; off <<= 1) p += __shfl_xor(p, off);
        if (c == 0) pubf(&gdst[i * G3 + row], p);
      }
      __syncthreads();
      m_node += 1 + i;
    }

  } else {
    // =================== HEATERS (keep SMU clocks up) ===================
    // Dependent-FMA chains (~25% VALU issue duty) + periodic poll of the
    // classifier's final decision word as exit flag. Deterministic, no
    // protocol participation; if a heater launches late it exits instantly.
    const unsigned int* flag = &ws->dec[MAXN - 1];
    float acc = (float)tid * 0.001f;
    const float bb = 1.0000001f, aa = 0.5f;
    for (;;) {
      unsigned int v = __hip_atomic_load(flag, __ATOMIC_RELAXED, __HIP_MEMORY_SCOPE_AGENT);
      if (v != SENTU) break;
      #pragma unroll 8
      for (int it = 0; it < 512; ++it) acc = __builtin_fmaf(acc, bb, aa);
    }
    asm volatile("" :: "v"(acc));   // keep the chain live (rule #17)
  }
}

extern "C" void kernel_launch(void* const* d_in, const int* in_sizes, int n_in,
                              void* d_out, int out_size, void* d_ws, size_t ws_size,
                              hipStream_t stream) {
  // sentinel-fill the communication workspace every call (graph-replay safe)
  hipMemsetAsync(d_ws, 0xFF, sizeof(Wksp), stream);
  Generator_34746285425383_kernel<<<dim3(NWG), dim3(256), 0, stream>>>(
      (const float*)d_in[0],  (const float*)d_in[1],  (const float*)d_in[2],
      (const float*)d_in[3],  (const float*)d_in[4],  (const float*)d_in[5],
      (const float*)d_in[6],  (const float*)d_in[7],  (const float*)d_in[8],
      (const float*)d_in[9],  (const float*)d_in[10],
      (const float*)d_in[11], (const float*)d_in[12],
      (const float*)d_in[13], (const float*)d_in[14],
      (const float*)d_in[15], (const float*)d_in[16],
      (const float*)d_in[17], (const float*)d_in[18],
      (const float*)d_in[19], (const float*)d_in[20],
      (float*)d_out, (Wksp*)d_ws);
}